// Round 17
// baseline (188.442 us; speedup 1.0000x reference)
//
#include <hip/hip_runtime.h>
#include <hip/hip_bf16.h>

#define N_NODES 25000
#define N_EDGES 100000
#define E_PAD   100096   // 782 * 128

typedef __attribute__((ext_vector_type(8))) short bf16x8;
typedef __attribute__((ext_vector_type(4))) float f32x4;

__device__ __forceinline__ unsigned short f2bf(float v) {
  __hip_bfloat16 hb = __float2bfloat16(v);
  return *reinterpret_cast<unsigned short*>(&hb);
}

__device__ __forceinline__ unsigned fkey(float f) {
  unsigned u = __float_as_uint(f);
  return (u & 0x80000000u) ? ~u : (u | 0x80000000u);
}
__device__ __forceinline__ float fdec(unsigned k) {
  return (k & 0x80000000u) ? __uint_as_float(k ^ 0x80000000u) : __uint_as_float(~k);
}

// Fused prep: blocks [0,128): W2 -> bf16 packed B-fragments. Blocks
// [128, 128+6250): node-side prep out/xb/ab1/ab2/mk/s_sum.
__global__ __launch_bounds__(256) void k_pre(const float* __restrict__ x,
    const float* __restrict__ root, const float* __restrict__ b2,
    const float* __restrict__ att, const float* __restrict__ bias,
    const float* __restrict__ W2, unsigned char* __restrict__ w2pk,
    float* __restrict__ out, float* __restrict__ xb,
    float* __restrict__ ab1, float* __restrict__ ab2,
    unsigned* __restrict__ mk, float* __restrict__ s_sum) {
  __shared__ float lxb[4][64];
  int b = blockIdx.x;
  if (b < 128) {
    int g = b * 256 + threadIdx.x;                 // 32768 threads
    int s = g & 3, lane = (g >> 2) & 63, w = (g >> 8) & 3, i = g >> 10;
    int col = i * 64 + w * 16 + (lane & 15);
    int k0 = s * 32 + (lane >> 4) * 8;
    bf16x8 v;
    #pragma unroll
    for (int j = 0; j < 8; ++j)
      v[j] = (short)f2bf(W2[(size_t)(k0 + j) * 2048 + col]);
    *(bf16x8*)(w2pk + (size_t)g * 16) = v;
    return;
  }
  int g = (b - 128) * 256 + threadIdx.x;           // N*64 exact
  int n = g >> 6, o = g & 63;
  const float* xr = x + (size_t)n * 32;
  float ra = bias[o], xa = 0.f;
  #pragma unroll
  for (int i = 0; i < 32; ++i) {
    float xv = xr[i];
    ra += xv * root[i * 64 + o];
    xa += xv * b2[i * 64 + o];
  }
  out[g] = ra;
  xb[g] = xa;
  int ln = threadIdx.x >> 6;
  lxb[ln][o] = xa;
  __syncthreads();
  if (o < 8) {
    int hd = o;
    float s1 = 0.f, s2 = 0.f;
    #pragma unroll
    for (int c = 0; c < 8; ++c) {
      float v = lxb[ln][hd * 8 + c];
      s1 += v * att[hd * 16 + c];
      s2 += v * att[hd * 16 + 8 + c];
    }
    size_t idx = (size_t)n * 8 + hd;
    ab1[idx] = s1; ab2[idx] = s2; mk[idx] = 0u; s_sum[idx] = 0.f;
  }
}

// R16's k_main, re-packed: 512 threads = 2 INDEPENDENT 64-edge tiles per
// workgroup (tile = tid>>8; within a tile everything is R16-verbatim).
// Tests the 2-WG/CU residency cap: same waves, same per-wave code, but
// 2x waves per resident WG. LDS 64 KB/WG (2x per-tile arrays).
__global__ __launch_bounds__(512)
__attribute__((amdgpu_waves_per_eu(2)))
void k_main(
    const float* __restrict__ x, const int* __restrict__ ei,
    const float* __restrict__ ef, const float* __restrict__ W1,
    const float* __restrict__ b1,
    const float* __restrict__ att, const float* __restrict__ ab1,
    const float* __restrict__ ab2,
    const unsigned char* __restrict__ w2pk,
    float* __restrict__ xj_out, float* __restrict__ alpha_out,
    unsigned* __restrict__ mk) {
  __shared__ unsigned char lds_h[2][16384];  // per-tile: 16 frags x 64 lanes x 16B
  __shared__ float lds_xs[2][32 * 64];       // per-tile: [ch][edge] x[src], f32
  __shared__ float lds_xd[2][32 * 64];       // per-tile: [ch][edge] x[dst], f32
  const int tid = threadIdx.x;
  const int tile = tid >> 8;                 // 0 or 1
  const int tt = tid & 255;                  // thread-in-tile
  const int lane = tt & 63;
  const int w = tt >> 6;                     // wave-in-tile: cols w*16..+15
  const int e0 = blockIdx.x * 128 + tile * 64;
  const int* srcp = ei;
  const int* dstp = ei + N_EDGES;

  // ---- inline h via MFMA (R13 mapping, proven absmax 0.0156) ----
  {
    const int l15 = lane & 15;
    const int k0 = (lane >> 4) * 8;
    bf16x8 ha[4], hb[2];
    #pragma unroll
    for (int mt = 0; mt < 4; ++mt) {
      int e = e0 + mt * 16 + l15;
      if (e >= N_EDGES) e = N_EDGES - 1;   // clamped rows masked later
      bf16x8 v;
      if (k0 < 16) {
        const float* ap = ef + (size_t)e * 16 + k0;
        f32x4 a0 = *(const f32x4*)(ap);
        f32x4 a1 = *(const f32x4*)(ap + 4);
        #pragma unroll
        for (int t = 0; t < 4; ++t) {
          v[t]     = (short)f2bf(a0[t]);
          v[t + 4] = (short)f2bf(a1[t]);
        }
      } else {
        #pragma unroll
        for (int t = 0; t < 8; ++t) v[t] = 0;
      }
      ha[mt] = v;
    }
    #pragma unroll
    for (int nt = 0; nt < 2; ++nt) {
      int col = w * 32 + nt * 16 + l15;
      bf16x8 v;
      if (k0 < 16) {
        #pragma unroll
        for (int j = 0; j < 8; ++j)
          v[j] = (short)f2bf(W1[(k0 + j) * 128 + col]);
      } else {
        #pragma unroll
        for (int j = 0; j < 8; ++j) v[j] = 0;
      }
      hb[nt] = v;
    }
    const int lpb = (lane >> 4) * 4;               // output row base within 16
    const int byt = (lane & 7) * 2;                // byte within 16B frag slot
    #pragma unroll
    for (int nt = 0; nt < 2; ++nt) {
      float bv = b1[w * 32 + nt * 16 + l15];
      const int hi = (nt * 2 + (l15 >> 3)) << 4;   // reader-lane hi nibble
      #pragma unroll
      for (int mt = 0; mt < 4; ++mt) {
        f32x4 acc = {bv, bv, bv, bv};
        acc = __builtin_amdgcn_mfma_f32_16x16x32_bf16(ha[mt], hb[nt], acc, 0, 0, 0);
        unsigned base = (unsigned)(mt * 4 + w) * 1024u + (unsigned)hi * 16u + (unsigned)byt;
        #pragma unroll
        for (int r = 0; r < 4; ++r) {
          float hv = acc[r] > 0.f ? acc[r] : 0.f;
          *(unsigned short*)(&lds_h[tile][0] + base + (lpb + r) * 16) = f2bf(hv);
        }
      }
    }
  }

  // ---- gather x rows for src/dst (transposed into LDS, f32) ----
  {
    int m = tt & 63;
    int half = (tt >> 6) & 1;
    int which = tt >> 7;
    int eIdx = e0 + m; if (eIdx >= N_EDGES) eIdx = N_EDGES - 1;
    int node = which ? dstp[eIdx] : srcp[eIdx];
    const f32x4* xr = (const f32x4*)(x + (size_t)node * 32 + half * 16);
    float* lx = which ? &lds_xd[tile][0] : &lds_xs[tile][0];
    #pragma unroll
    for (int q = 0; q < 4; ++q) {
      f32x4 vv = xr[q];
      int i0 = half * 16 + q * 4;
      #pragma unroll
      for (int j = 0; j < 4; ++j) lx[(i0 + j) * 64 + m] = vv[j];
    }
  }
  __syncthreads();

  // ---- K-loop: pair-amortized (one A-read feeds both chunks) ----
  const unsigned char* bgp = w2pk + (size_t)w * 4096 + (size_t)lane * 64;
  f32x4 xj_acc[4] = {};
  f32x4 xi_acc[4] = {};
  const int rg4 = ((lane >> 4) & 3) * 4;
  const int lb16 = lane * 16;

  #pragma unroll 1
  for (int p = 0; p < 16; ++p) {
    const int i = 2 * p;
    bf16x8 bA[4], bB[4];
    #pragma unroll
    for (int s = 0; s < 4; ++s) {
      bA[s] = *(const bf16x8*)(bgp + (size_t)i * 16384 + s * 16);
      bB[s] = *(const bf16x8*)(bgp + (size_t)(i + 1) * 16384 + s * 16);
    }
    #pragma unroll
    for (int mt = 0; mt < 4; ++mt) {
      f32x4 gA = {0.f, 0.f, 0.f, 0.f};
      f32x4 gB = {0.f, 0.f, 0.f, 0.f};
      #pragma unroll
      for (int s = 0; s < 4; ++s) {
        bf16x8 a = *(const bf16x8*)(&lds_h[tile][0] + (mt * 4 + s) * 1024 + lb16);
        gA = __builtin_amdgcn_mfma_f32_16x16x32_bf16(a, bA[s], gA, 0, 0, 0);
        gB = __builtin_amdgcn_mfma_f32_16x16x32_bf16(a, bB[s], gB, 0, 0, 0);
      }
      f32x4 xsv0 = *(const f32x4*)(&lds_xs[tile][0] + i * 64 + mt * 16 + rg4);
      f32x4 xdv0 = *(const f32x4*)(&lds_xd[tile][0] + i * 64 + mt * 16 + rg4);
      f32x4 xsv1 = *(const f32x4*)(&lds_xs[tile][0] + (i + 1) * 64 + mt * 16 + rg4);
      f32x4 xdv1 = *(const f32x4*)(&lds_xd[tile][0] + (i + 1) * 64 + mt * 16 + rg4);
      #pragma unroll
      for (int r = 0; r < 4; ++r) {
        xj_acc[mt][r] += xsv0[r] * gA[r] + xsv1[r] * gB[r];
        xi_acc[mt][r] += xdv0[r] * gA[r] + xdv1[r] * gB[r];
      }
    }
  }

  // ---- epilogue (R13 verbatim, per tile) ----
  const int h2 = (lane >> 3) & 1;
  const int cc = lane & 7;
  const int head = 2 * w + h2;
  const float a1v = att[head * 16 + cc];
  const float a2v = att[head * 16 + 8 + cc];
  #pragma unroll
  for (int mt = 0; mt < 4; ++mt) {
    #pragma unroll
    for (int r = 0; r < 4; ++r) {
      int row = mt * 16 + rg4 + r;
      int eIdx = e0 + row;
      xj_out[(size_t)eIdx * 64 + w * 16 + (lane & 15)] = xj_acc[mt][r];
      float v = xi_acc[mt][r] * a1v + xj_acc[mt][r] * a2v;
      v += __shfl_xor(v, 1);
      v += __shfl_xor(v, 2);
      v += __shfl_xor(v, 4);
      if (cc == 0 && eIdx < N_EDGES) {
        int d = dstp[eIdx];
        float lg = v + ab1[(size_t)d * 8 + head] + ab2[(size_t)srcp[eIdx] * 8 + head];
        lg = lg > 0.f ? lg : 0.2f * lg;
        alpha_out[(size_t)eIdx * 8 + head] = lg;
        atomicMax(mk + (size_t)d * 8 + head, fkey(lg));
      }
    }
  }
}

__global__ __launch_bounds__(256) void k_exp(float* __restrict__ alpha,
    const int* __restrict__ ei, const unsigned* __restrict__ mk, float* __restrict__ s) {
  int g = blockIdx.x * 256 + threadIdx.x;          // E*8 exact
  int e = g >> 3, hd = g & 7;
  int d = ei[N_EDGES + e];
  float ea = expf(alpha[g] - fdec(mk[(size_t)d * 8 + hd]));
  alpha[g] = ea;
  atomicAdd(s + (size_t)d * 8 + hd, ea);
}

__global__ __launch_bounds__(256) void k_scatter(const float* __restrict__ xj,
    const float* __restrict__ xb, const float* __restrict__ alpha,
    const float* __restrict__ s, const int* __restrict__ ei,
    const float* __restrict__ bias, float* __restrict__ out) {
  int g = blockIdx.x * 256 + threadIdx.x;          // E*64 exact
  int e = g >> 6, o = g & 63, hd = o >> 3;
  int sidx = ei[e], d = ei[N_EDGES + e];
  float ea = alpha[(size_t)e * 8 + hd];
  float sv = s[(size_t)d * 8 + hd];
  float val = (xj[g] + xb[(size_t)sidx * 64 + o]) * (ea / (sv + 1e-16f)) + bias[o];
  atomicAdd(out + (size_t)d * 64 + o, val);
}

__global__ __launch_bounds__(256) void k_elu(float* __restrict__ out) {
  int g = blockIdx.x * 256 + threadIdx.x;          // N*64 exact
  float v = out[g];
  out[g] = v > 0.f ? v : expm1f(v);
}

extern "C" void kernel_launch(void* const* d_in, const int* in_sizes, int n_in,
                              void* d_out, int out_size, void* d_ws, size_t ws_size,
                              hipStream_t stream) {
  const float* x    = (const float*)d_in[0];
  const int*   eidx = (const int*)d_in[1];
  const float* ef   = (const float*)d_in[2];
  const float* W1   = (const float*)d_in[3];
  const float* b1   = (const float*)d_in[4];
  const float* W2   = (const float*)d_in[5];
  const float* b2   = (const float*)d_in[6];
  const float* att  = (const float*)d_in[7];
  const float* bias = (const float*)d_in[8];
  const float* root = (const float*)d_in[9];
  float* out = (float*)d_out;
  char* ws = (char*)d_ws;

  // workspace layout (256B aligned), total ~39 MB
  unsigned char* w2pk = (unsigned char*)(ws + 0);           // 512 KB packed B-frags
  float* xb    = (float*)(ws + 524288);                     // N*64 f32
  float* ab1   = (float*)(ws + 6924288);                    // N*8 f32
  float* ab2   = (float*)(ws + 7724288);                    // N*8 f32
  float* xj_ws = (float*)(ws + 8524288);                    // E_PAD*64 f32
  float* al_ws = (float*)(ws + 34148864);                   // E_PAD*8 f32
  unsigned* mk = (unsigned*)(ws + 37351936);                // N*8 u32
  float* s_sum = (float*)(ws + 38151936);                   // N*8 f32

  k_pre  <<<128 + N_NODES * 64 / 256, 256, 0, stream>>>(x, root, b2, att, bias,
                                                  W2, w2pk, out, xb, ab1, ab2, mk, s_sum);
  k_main <<<E_PAD / 128, 512, 0, stream>>>(x, eidx, ef, W1, b1, att, ab1, ab2,
                                           w2pk, xj_ws, al_ws, mk);
  k_exp  <<<N_EDGES * 8 / 256, 256, 0, stream>>>(al_ws, eidx, mk, s_sum);
  k_scatter<<<N_EDGES * 64 / 256, 256, 0, stream>>>(xj_ws, xb, al_ws, s_sum, eidx, bias, out);
  k_elu  <<<N_NODES * 64 / 256, 256, 0, stream>>>(out);
}

// Round 18
// 155.297 us; speedup vs baseline: 1.2134x; 1.2134x over previous
//
#include <hip/hip_runtime.h>
#include <hip/hip_bf16.h>

#define N_NODES 25000
#define N_EDGES 100000
#define E_PAD   100032   // 1563 * 64

typedef __attribute__((ext_vector_type(8))) short bf16x8;
typedef __attribute__((ext_vector_type(4))) float f32x4;

__device__ __forceinline__ unsigned short f2bf(float v) {
  __hip_bfloat16 hb = __float2bfloat16(v);
  return *reinterpret_cast<unsigned short*>(&hb);
}

__device__ __forceinline__ unsigned fkey(float f) {
  unsigned u = __float_as_uint(f);
  return (u & 0x80000000u) ? ~u : (u | 0x80000000u);
}
__device__ __forceinline__ float fdec(unsigned k) {
  return (k & 0x80000000u) ? __uint_as_float(k ^ 0x80000000u) : __uint_as_float(~k);
}

// Fused prep: blocks [0,128): W2 -> bf16 packed B-fragments in COALESCED
// (i, w, s, lane) order: frag addr = i*16384 + w*4096 + s*1024 + lane*16,
// holding W2[k0..k0+8][i*64 + w*16 + (lane&15)], k0 = s*32 + (lane>>4)*8.
// (R2-R17 used lane-stride-64 order: each wave B-load touched 64 cache lines
// -> 4x L2 traffic, ~90 us of k_main. lane*16 makes it one 1KB transaction.)
// Blocks [128, 128+6250): node-side prep out/xb/ab1/ab2/mk/s_sum.
__global__ __launch_bounds__(256) void k_pre(const float* __restrict__ x,
    const float* __restrict__ root, const float* __restrict__ b2,
    const float* __restrict__ att, const float* __restrict__ bias,
    const float* __restrict__ W2, unsigned char* __restrict__ w2pk,
    float* __restrict__ out, float* __restrict__ xb,
    float* __restrict__ ab1, float* __restrict__ ab2,
    unsigned* __restrict__ mk, float* __restrict__ s_sum) {
  __shared__ float lxb[4][64];
  int b = blockIdx.x;
  if (b < 128) {
    int g = b * 256 + threadIdx.x;                 // 32768 threads
    int lane = g & 63, s = (g >> 6) & 3, w = (g >> 8) & 3, i = g >> 10;
    int col = i * 64 + w * 16 + (lane & 15);
    int k0 = s * 32 + (lane >> 4) * 8;
    bf16x8 v;
    #pragma unroll
    for (int j = 0; j < 8; ++j)
      v[j] = (short)f2bf(W2[(size_t)(k0 + j) * 2048 + col]);
    *(bf16x8*)(w2pk + (size_t)g * 16) = v;         // linear: coalesced store
    return;
  }
  int g = (b - 128) * 256 + threadIdx.x;           // N*64 exact
  int n = g >> 6, o = g & 63;
  const float* xr = x + (size_t)n * 32;
  float ra = bias[o], xa = 0.f;
  #pragma unroll
  for (int i = 0; i < 32; ++i) {
    float xv = xr[i];
    ra += xv * root[i * 64 + o];
    xa += xv * b2[i * 64 + o];
  }
  out[g] = ra;
  xb[g] = xa;
  int ln = threadIdx.x >> 6;
  lxb[ln][o] = xa;
  __syncthreads();
  if (o < 8) {
    int hd = o;
    float s1 = 0.f, s2 = 0.f;
    #pragma unroll
    for (int c = 0; c < 8; ++c) {
      float v = lxb[ln][hd * 8 + c];
      s1 += v * att[hd * 16 + c];
      s2 += v * att[hd * 16 + 8 + c];
    }
    size_t idx = (size_t)n * 8 + hd;
    ab1[idx] = s1; ab2[idx] = s2; mk[idx] = 0u; s_sum[idx] = 0.f;
  }
}

// R16 k_main verbatim except B-load addressing matches the new coalesced
// w2pk layout: bgp = w2pk + w*4096 + lane*16; frag s of chunk i at
// bgp + i*16384 + s*1024 (one contiguous 1KB wave transaction per load).
__global__ __launch_bounds__(256)
__attribute__((amdgpu_waves_per_eu(2)))
void k_main(
    const float* __restrict__ x, const int* __restrict__ ei,
    const float* __restrict__ ef, const float* __restrict__ W1,
    const float* __restrict__ b1,
    const float* __restrict__ att, const float* __restrict__ ab1,
    const float* __restrict__ ab2,
    const unsigned char* __restrict__ w2pk,
    float* __restrict__ xj_out, float* __restrict__ alpha_out,
    unsigned* __restrict__ mk) {
  __shared__ unsigned char lds_h[16384];   // 16 frags x 64 lanes x 16B, linear
  __shared__ float lds_xs[32 * 64];        // [ch][edge] x[src] transposed, f32
  __shared__ float lds_xd[32 * 64];        // [ch][edge] x[dst] transposed, f32
  const int tid = threadIdx.x;
  const int lane = tid & 63;
  const int w = tid >> 6;                  // wave id: owns output cols w*16..+15
  const int e0 = blockIdx.x * 64;
  const int* srcp = ei;
  const int* dstp = ei + N_EDGES;

  // ---- inline h via MFMA (R13 verbatim, proven absmax 0.0156) ----
  {
    const int l15 = lane & 15;
    const int k0 = (lane >> 4) * 8;
    bf16x8 ha[4], hb[2];
    #pragma unroll
    for (int mt = 0; mt < 4; ++mt) {
      int e = e0 + mt * 16 + l15;
      if (e >= N_EDGES) e = N_EDGES - 1;   // clamped rows masked later
      bf16x8 v;
      if (k0 < 16) {
        const float* ap = ef + (size_t)e * 16 + k0;
        f32x4 a0 = *(const f32x4*)(ap);
        f32x4 a1 = *(const f32x4*)(ap + 4);
        #pragma unroll
        for (int t = 0; t < 4; ++t) {
          v[t]     = (short)f2bf(a0[t]);
          v[t + 4] = (short)f2bf(a1[t]);
        }
      } else {
        #pragma unroll
        for (int t = 0; t < 8; ++t) v[t] = 0;
      }
      ha[mt] = v;
    }
    #pragma unroll
    for (int nt = 0; nt < 2; ++nt) {
      int col = w * 32 + nt * 16 + l15;
      bf16x8 v;
      if (k0 < 16) {
        #pragma unroll
        for (int j = 0; j < 8; ++j)
          v[j] = (short)f2bf(W1[(k0 + j) * 128 + col]);
      } else {
        #pragma unroll
        for (int j = 0; j < 8; ++j) v[j] = 0;
      }
      hb[nt] = v;
    }
    const int lpb = (lane >> 4) * 4;               // output row base within 16
    const int byt = (lane & 7) * 2;                // byte within 16B frag slot
    #pragma unroll
    for (int nt = 0; nt < 2; ++nt) {
      float bv = b1[w * 32 + nt * 16 + l15];
      const int hi = (nt * 2 + (l15 >> 3)) << 4;   // reader-lane hi nibble
      #pragma unroll
      for (int mt = 0; mt < 4; ++mt) {
        f32x4 acc = {bv, bv, bv, bv};
        acc = __builtin_amdgcn_mfma_f32_16x16x32_bf16(ha[mt], hb[nt], acc, 0, 0, 0);
        unsigned base = (unsigned)(mt * 4 + w) * 1024u + (unsigned)hi * 16u + (unsigned)byt;
        #pragma unroll
        for (int r = 0; r < 4; ++r) {
          float hv = acc[r] > 0.f ? acc[r] : 0.f;
          *(unsigned short*)(lds_h + base + (lpb + r) * 16) = f2bf(hv);
        }
      }
    }
  }

  // ---- gather x rows for src/dst (transposed into LDS, f32) ----
  {
    int m = tid & 63;
    int half = (tid >> 6) & 1;
    int which = tid >> 7;
    int eIdx = e0 + m; if (eIdx >= N_EDGES) eIdx = N_EDGES - 1;
    int node = which ? dstp[eIdx] : srcp[eIdx];
    const f32x4* xr = (const f32x4*)(x + (size_t)node * 32 + half * 16);
    float* lx = which ? lds_xd : lds_xs;
    #pragma unroll
    for (int q = 0; q < 4; ++q) {
      f32x4 vv = xr[q];
      int i0 = half * 16 + q * 4;
      #pragma unroll
      for (int j = 0; j < 4; ++j) lx[(i0 + j) * 64 + m] = vv[j];
    }
  }
  __syncthreads();

  // ---- K-loop: pair-amortized, coalesced B-loads ----
  const unsigned char* bgp = w2pk + (size_t)w * 4096 + (size_t)lane * 16;
  f32x4 xj_acc[4] = {};
  f32x4 xi_acc[4] = {};
  const int rg4 = ((lane >> 4) & 3) * 4;
  const int lb16 = lane * 16;

  #pragma unroll 1
  for (int p = 0; p < 16; ++p) {
    const int i = 2 * p;
    bf16x8 bA[4], bB[4];
    #pragma unroll
    for (int s = 0; s < 4; ++s) {
      bA[s] = *(const bf16x8*)(bgp + (size_t)i * 16384 + s * 1024);
      bB[s] = *(const bf16x8*)(bgp + (size_t)(i + 1) * 16384 + s * 1024);
    }
    #pragma unroll
    for (int mt = 0; mt < 4; ++mt) {
      f32x4 gA = {0.f, 0.f, 0.f, 0.f};
      f32x4 gB = {0.f, 0.f, 0.f, 0.f};
      #pragma unroll
      for (int s = 0; s < 4; ++s) {
        bf16x8 a = *(const bf16x8*)(lds_h + (mt * 4 + s) * 1024 + lb16);
        gA = __builtin_amdgcn_mfma_f32_16x16x32_bf16(a, bA[s], gA, 0, 0, 0);
        gB = __builtin_amdgcn_mfma_f32_16x16x32_bf16(a, bB[s], gB, 0, 0, 0);
      }
      f32x4 xsv0 = *(const f32x4*)(lds_xs + i * 64 + mt * 16 + rg4);
      f32x4 xdv0 = *(const f32x4*)(lds_xd + i * 64 + mt * 16 + rg4);
      f32x4 xsv1 = *(const f32x4*)(lds_xs + (i + 1) * 64 + mt * 16 + rg4);
      f32x4 xdv1 = *(const f32x4*)(lds_xd + (i + 1) * 64 + mt * 16 + rg4);
      #pragma unroll
      for (int r = 0; r < 4; ++r) {
        xj_acc[mt][r] += xsv0[r] * gA[r] + xsv1[r] * gB[r];
        xi_acc[mt][r] += xdv0[r] * gA[r] + xdv1[r] * gB[r];
      }
    }
  }

  // ---- epilogue (R13 verbatim) ----
  const int h2 = (lane >> 3) & 1;
  const int cc = lane & 7;
  const int head = 2 * w + h2;
  const float a1v = att[head * 16 + cc];
  const float a2v = att[head * 16 + 8 + cc];
  #pragma unroll
  for (int mt = 0; mt < 4; ++mt) {
    #pragma unroll
    for (int r = 0; r < 4; ++r) {
      int row = mt * 16 + rg4 + r;
      int eIdx = e0 + row;
      xj_out[(size_t)eIdx * 64 + w * 16 + (lane & 15)] = xj_acc[mt][r];
      float v = xi_acc[mt][r] * a1v + xj_acc[mt][r] * a2v;
      v += __shfl_xor(v, 1);
      v += __shfl_xor(v, 2);
      v += __shfl_xor(v, 4);
      if (cc == 0 && eIdx < N_EDGES) {
        int d = dstp[eIdx];
        float lg = v + ab1[(size_t)d * 8 + head] + ab2[(size_t)srcp[eIdx] * 8 + head];
        lg = lg > 0.f ? lg : 0.2f * lg;
        alpha_out[(size_t)eIdx * 8 + head] = lg;
        atomicMax(mk + (size_t)d * 8 + head, fkey(lg));
      }
    }
  }
}

__global__ __launch_bounds__(256) void k_exp(float* __restrict__ alpha,
    const int* __restrict__ ei, const unsigned* __restrict__ mk, float* __restrict__ s) {
  int g = blockIdx.x * 256 + threadIdx.x;          // E*8 exact
  int e = g >> 3, hd = g & 7;
  int d = ei[N_EDGES + e];
  float ea = expf(alpha[g] - fdec(mk[(size_t)d * 8 + hd]));
  alpha[g] = ea;
  atomicAdd(s + (size_t)d * 8 + hd, ea);
}

__global__ __launch_bounds__(256) void k_scatter(const float* __restrict__ xj,
    const float* __restrict__ xb, const float* __restrict__ alpha,
    const float* __restrict__ s, const int* __restrict__ ei,
    const float* __restrict__ bias, float* __restrict__ out) {
  int g = blockIdx.x * 256 + threadIdx.x;          // E*64 exact
  int e = g >> 6, o = g & 63, hd = o >> 3;
  int sidx = ei[e], d = ei[N_EDGES + e];
  float ea = alpha[(size_t)e * 8 + hd];
  float sv = s[(size_t)d * 8 + hd];
  float val = (xj[g] + xb[(size_t)sidx * 64 + o]) * (ea / (sv + 1e-16f)) + bias[o];
  atomicAdd(out + (size_t)d * 64 + o, val);
}

__global__ __launch_bounds__(256) void k_elu(float* __restrict__ out) {
  int g = blockIdx.x * 256 + threadIdx.x;          // N*64 exact
  float v = out[g];
  out[g] = v > 0.f ? v : expm1f(v);
}

extern "C" void kernel_launch(void* const* d_in, const int* in_sizes, int n_in,
                              void* d_out, int out_size, void* d_ws, size_t ws_size,
                              hipStream_t stream) {
  const float* x    = (const float*)d_in[0];
  const int*   eidx = (const int*)d_in[1];
  const float* ef   = (const float*)d_in[2];
  const float* W1   = (const float*)d_in[3];
  const float* b1   = (const float*)d_in[4];
  const float* W2   = (const float*)d_in[5];
  const float* b2   = (const float*)d_in[6];
  const float* att  = (const float*)d_in[7];
  const float* bias = (const float*)d_in[8];
  const float* root = (const float*)d_in[9];
  float* out = (float*)d_out;
  char* ws = (char*)d_ws;

  // workspace layout (256B aligned), total ~39 MB
  unsigned char* w2pk = (unsigned char*)(ws + 0);           // 512 KB packed B-frags
  float* xb    = (float*)(ws + 524288);                     // N*64 f32
  float* ab1   = (float*)(ws + 6924288);                    // N*8 f32
  float* ab2   = (float*)(ws + 7724288);                    // N*8 f32
  float* xj_ws = (float*)(ws + 8524288);                    // E_PAD*64 f32
  float* al_ws = (float*)(ws + 34132480);                   // E_PAD*8 f32
  unsigned* mk = (unsigned*)(ws + 37333504);                // N*8 u32
  float* s_sum = (float*)(ws + 38133504);                   // N*8 f32

  k_pre  <<<128 + N_NODES * 64 / 256, 256, 0, stream>>>(x, root, b2, att, bias,
                                                  W2, w2pk, out, xb, ab1, ab2, mk, s_sum);
  k_main <<<E_PAD / 64, 256, 0, stream>>>(x, eidx, ef, W1, b1, att, ab1, ab2,
                                          w2pk, xj_ws, al_ws, mk);
  k_exp  <<<N_EDGES * 8 / 256, 256, 0, stream>>>(al_ws, eidx, mk, s_sum);
  k_scatter<<<N_EDGES * 64 / 256, 256, 0, stream>>>(xj_ws, xb, al_ws, s_sum, eidx, bias, out);
  k_elu  <<<N_NODES * 64 / 256, 256, 0, stream>>>(out);
}